// Round 13
// baseline (241.604 us; speedup 1.0000x reference)
//
#include <hip/hip_runtime.h>

// EnvironmentalAugmentations: pink = AR(1) scan of white noise (a=0.99, b=0.01),
// mixed = waveform + 0.05*pink, out = mixed / max(|mixed|) if max > 1 else mixed.
// Shapes: (256 channels, 220500 samples), f32 in / f32 out.
//
// R1-R12 synthesis: streaming BW on this op is a pure function of resident
// waves, which follows waves/SIMD = floor(256/VGPR): VGPR 20 -> 83% occ ->
// 5.2 TB/s (R8 apply); VGPR 52-60 -> ~40% occ -> 2.7-3.2 TB/s (all fused
// variants). R13: fused kernel with apply's register footprint: segment 2048
// + 512 warm-up, processed as 4 sequential 512-sample sub-blocks (4 float4
// live at a time, E chained in one scalar). Warm-up = weighted wave sum-
// reduction. launch_bounds(256,7) caps VGPR ~36 -> 7-8 waves/SIMD.

#define TLEN 220500
#define CHANNELS 256

constexpr int SEGL = 2048;                        // samples per segment (1 wave)
constexpr int SUB  = 512;                         // sub-block (64 lanes x 8)
constexpr int WUP  = 512;                         // warm-up samples
constexpr int SPC  = (TLEN + SEGL - 1) / SEGL;    // 108 segments per channel
constexpr int NSEG = SPC * CHANNELS;              // 27648 segments
constexpr int NBLOCKS = 2048;                     // persistent blocks
constexpr int GRID_WAVES = NBLOCKS * 4;           // 8192 waves

constexpr float AC = 0.99f;
constexpr float BC = 0.01f;
constexpr float NL = 0.05f;

constexpr double dpow(double a, long n) { double r = 1.0; for (long i = 0; i < n; ++i) r *= a; return r; }

// wave scan multipliers at 8-sample granularity: 0.99^(8d)
constexpr float S8P0 = (float)dpow(0.99, 8);
constexpr float S8P1 = (float)dpow(0.99, 16);
constexpr float S8P2 = (float)dpow(0.99, 32);
constexpr float S8P3 = (float)dpow(0.99, 64);
constexpr float S8P4 = (float)dpow(0.99, 128);
constexpr float S8P5 = (float)dpow(0.99, 256);
constexpr float A512 = (float)dpow(0.99, 512);    // sub-block decay
constexpr float L2A8 = -0.11599655756609923f;     // 8 * log2(0.99)

// native vector type for nontemporal builtins (same layout as float4)
typedef float f4 __attribute__((ext_vector_type(4)));

__device__ __forceinline__ f4 ntld4(const float* p) {
    return __builtin_nontemporal_load(reinterpret_cast<const f4*>(p));
}

__device__ __forceinline__ float wave_scan8(float f, int lane) {
    { float o = __shfl_up(f, 1,  64); if (lane >= 1)  f = fmaf(S8P0, o, f); }
    { float o = __shfl_up(f, 2,  64); if (lane >= 2)  f = fmaf(S8P1, o, f); }
    { float o = __shfl_up(f, 4,  64); if (lane >= 4)  f = fmaf(S8P2, o, f); }
    { float o = __shfl_up(f, 8,  64); if (lane >= 8)  f = fmaf(S8P3, o, f); }
    { float o = __shfl_up(f, 16, 64); if (lane >= 16) f = fmaf(S8P4, o, f); }
    { float o = __shfl_up(f, 32, 64); if (lane >= 32) f = fmaf(S8P5, o, f); }
    return f;
}

__device__ __forceinline__ float serial8(const f4& a, const f4& b) {
    float f = BC * a.x;
    f = fmaf(AC, f, BC * a.y);
    f = fmaf(AC, f, BC * a.z);
    f = fmaf(AC, f, BC * a.w);
    f = fmaf(AC, f, BC * b.x);
    f = fmaf(AC, f, BC * b.y);
    f = fmaf(AC, f, BC * b.z);
    f = fmaf(AC, f, BC * b.w);
    return f;
}

__global__ void init_max_kernel(unsigned int* gmax) { *gmax = 0u; }

// USE_ATOMIC=1 is the fallback (ws too small): atomicMax into gmax.
template <int USE_ATOMIC>
__global__ __launch_bounds__(256, 7)
void fused_kernel(const float* __restrict__ waveform,
                  const float* __restrict__ white,
                  float* __restrict__ out,
                  unsigned int* __restrict__ gmax,
                  float* __restrict__ blockmax)
{
    __shared__ float sM[4];
    const int tid  = threadIdx.x;
    const int lane = tid & 63;
    const int wv   = tid >> 6;
    const int l8   = 8 * lane;
    const float D8L = __builtin_exp2f((float)lane * L2A8);        // 0.99^(8*lane)
    const float WSC = __builtin_exp2f((float)(63 - lane) * L2A8); // 0.99^(8*(63-lane))
    const f4 z4 = {0.f, 0.f, 0.f, 0.f};

    float mx = 0.f;

    // ---- grid-stride over segments: persistent blocks ----
    for (int S = blockIdx.x * 4 + wv; S < NSEG; S += GRID_WAVES) {
        const int ch = S / SPC;
        const int s  = S - ch * SPC;
        const size_t row = (size_t)ch * TLEN;
        const float* __restrict__ wrow = white + row;
        const float* __restrict__ arow = waveform + row;
        float* __restrict__ orow = out + row;
        const int seg0 = s * SEGL;

        // ---- entry state: weighted wave sum-reduction over 512 warm-up ----
        float E;
        if (s > 0) {
            const float* wb = wrow + (seg0 - WUP) + l8;    // always in-bounds
            f4 u0 = ntld4(wb);
            f4 u1 = ntld4(wb + 4);
            float fw = serial8(u0, u1) * WSC;              // weight a^(8*(63-l))
            #pragma unroll
            for (int d = 32; d >= 1; d >>= 1)
                fw += __shfl_xor(fw, d, 64);
            E = fw;
        } else {
            E = wrow[0];    // E = w[0] exact: a*w0 + b*w0 = w0 = pink[0]
        }

        // ---- 4 sequential sub-blocks of 512; only 4 float4 live at a time ----
        #pragma unroll
        for (int k = 0; k < 4; ++k) {
            const int g = seg0 + k * SUB + l8;
            f4 W0 = z4, W1 = z4, A0 = z4, A1 = z4;
            if (g < TLEN) {                                // g%4==0, TLEN%4==0
                W0 = ntld4(wrow + g);
                A0 = ntld4(arow + g);
            }
            if (g + 4 < TLEN) {
                W1 = ntld4(wrow + g + 4);
                A1 = ntld4(arow + g + 4);
            }
            float f  = serial8(W0, W1);
            float p  = wave_scan8(f, lane);
            float e  = __shfl_up(p, 1, 64);
            if (lane == 0) e = 0.f;
            const float T = __shfl(p, 63, 64);

            f = fmaf(D8L, E, e);                           // lane entry state
            f4 m0, m1;
            f = fmaf(AC, f, BC * W0.x); m0.x = fmaf(NL, f, A0.x);
            f = fmaf(AC, f, BC * W0.y); m0.y = fmaf(NL, f, A0.y);
            f = fmaf(AC, f, BC * W0.z); m0.z = fmaf(NL, f, A0.z);
            f = fmaf(AC, f, BC * W0.w); m0.w = fmaf(NL, f, A0.w);
            f = fmaf(AC, f, BC * W1.x); m1.x = fmaf(NL, f, A1.x);
            f = fmaf(AC, f, BC * W1.y); m1.y = fmaf(NL, f, A1.y);
            f = fmaf(AC, f, BC * W1.z); m1.z = fmaf(NL, f, A1.z);
            f = fmaf(AC, f, BC * W1.w); m1.w = fmaf(NL, f, A1.w);

            if (g < TLEN) {                                // regular store -> LLC
                *reinterpret_cast<f4*>(orow + g) = m0;
                mx = fmaxf(mx, fmaxf(fmaxf(fabsf(m0.x), fabsf(m0.y)),
                                     fmaxf(fabsf(m0.z), fabsf(m0.w))));
            }
            if (g + 4 < TLEN) {
                *reinterpret_cast<f4*>(orow + g + 4) = m1;
                mx = fmaxf(mx, fmaxf(fmaxf(fabsf(m1.x), fabsf(m1.y)),
                                     fmaxf(fabsf(m1.z), fabsf(m1.w))));
            }
            E = fmaf(A512, E, T);                          // advance sub-block
        }
    }

    // ---- block max ----
    #pragma unroll
    for (int d = 32; d >= 1; d >>= 1)
        mx = fmaxf(mx, __shfl_xor(mx, d, 64));
    if (lane == 0) sM[wv] = mx;
    __syncthreads();
    if (tid == 0) {
        float m = fmaxf(fmaxf(sM[0], sM[1]), fmaxf(sM[2], sM[3]));
        if (USE_ATOMIC) {
            atomicMax(gmax, __float_as_uint(m));           // values >= 0
        } else {
            blockmax[blockIdx.x] = m;
        }
    }
}

// reduce NBLOCKS block maxima -> gmax (float bits as uint)
__global__ __launch_bounds__(256)
void reduce_max_kernel(const float* __restrict__ blockmax, unsigned int* __restrict__ gmax)
{
    __shared__ float sM[4];
    const int tid  = threadIdx.x;
    const int lane = tid & 63;
    const int wv   = tid >> 6;
    float mx = 0.f;
    for (int i = tid; i < NBLOCKS; i += 256)
        mx = fmaxf(mx, blockmax[i]);
    #pragma unroll
    for (int d = 32; d >= 1; d >>= 1)
        mx = fmaxf(mx, __shfl_xor(mx, d, 64));
    if (lane == 0) sM[wv] = mx;
    __syncthreads();
    if (tid == 0)
        *gmax = __float_as_uint(fmaxf(fmaxf(sM[0], sM[1]), fmaxf(sM[2], sM[3])));
}

__global__ __launch_bounds__(256)
void scale_kernel(float* __restrict__ out, const unsigned int* __restrict__ gmax, int n4)
{
    const float m = __uint_as_float(*gmax);
    const float s = (m > 1.0f) ? (1.0f / m) : 1.0f;
    f4* p = reinterpret_cast<f4*>(out);
    int i = blockIdx.x * blockDim.x + threadIdx.x;
    const int stride = gridDim.x * blockDim.x;
    for (; i < n4; i += stride) {
        f4 v = p[i];                             // LLC-warm read
        v.x *= s; v.y *= s; v.z *= s; v.w *= s;
        __builtin_nontemporal_store(v, &p[i]);   // final data: bypass LLC
    }
}

extern "C" void kernel_launch(void* const* d_in, const int* in_sizes, int n_in,
                              void* d_out, int out_size, void* d_ws, size_t ws_size,
                              hipStream_t stream)
{
    const float* waveform = (const float*)d_in[0];
    const float* white    = (const float*)d_in[1];
    float* out            = (float*)d_out;

    // ws layout: gmax @0 (256B reserved) | blockmax @256 (NBLOCKS floats)
    unsigned int* gmax = (unsigned int*)d_ws;
    float* blockmax    = (float*)((char*)d_ws + 256);
    const bool ws_ok   = ws_size >= 256 + (size_t)NBLOCKS * sizeof(float);

    const int n4 = out_size / 4;           // 14,112,000 float4s

    if (ws_ok) {
        hipLaunchKernelGGL((fused_kernel<0>), dim3(NBLOCKS), dim3(256), 0, stream,
                           waveform, white, out, gmax, blockmax);
        hipLaunchKernelGGL(reduce_max_kernel, dim3(1), dim3(256), 0, stream,
                           blockmax, gmax);
    } else {
        hipLaunchKernelGGL(init_max_kernel, dim3(1), dim3(1), 0, stream, gmax);
        hipLaunchKernelGGL((fused_kernel<1>), dim3(NBLOCKS), dim3(256), 0, stream,
                           waveform, white, out, gmax, blockmax);
    }
    hipLaunchKernelGGL(scale_kernel, dim3(3072), dim3(256), 0, stream,
                       out, gmax, n4);
}